// Round 9
// baseline (278.304 us; speedup 1.0000x reference)
//
#include <hip/hip_runtime.h>
#include <stdint.h>

#define EPS 1e-8f

typedef __attribute__((ext_vector_type(8))) __bf16 bf16x8;
typedef __attribute__((ext_vector_type(4))) float f32x4;

static constexpr int BO = 6400;   // B*O
static constexpr int AA = 16;     // attributes
static constexpr int DD = 1024;   // D
static constexpr int HH = 512;    // H

// ---------- helpers ----------
__device__ __forceinline__ unsigned short f2bf(float x) {
    uint32_t b = __float_as_uint(x);
    b += 0x7fffu + ((b >> 16) & 1u);   // round-to-nearest-even (finite inputs)
    return (unsigned short)(b >> 16);
}

__device__ __forceinline__ float fast_tanh(float x) {
    float e = __expf(2.0f * x);
    return 1.0f - __fdividef(2.0f, e + 1.0f);
}

// ---------- kernel 1: f32 -> bf16 staging of W_obj only ----------
__global__ __launch_bounds__(256) void k_prep_w(const float* __restrict__ W,
                                                unsigned short* __restrict__ W_bf) {
    const int i = blockIdx.x * 256 + threadIdx.x;   // 65536 8-elem units
    const long off = (long)i * 8;
    float4 v0 = *(const float4*)(W + off);
    float4 v1 = *(const float4*)(W + off + 4);
    union { unsigned short u[8]; int4 v; } pk;
    pk.u[0] = f2bf(v0.x); pk.u[1] = f2bf(v0.y); pk.u[2] = f2bf(v0.z); pk.u[3] = f2bf(v0.w);
    pk.u[4] = f2bf(v1.x); pk.u[5] = f2bf(v1.y); pk.u[6] = f2bf(v1.z); pk.u[7] = f2bf(v1.w);
    *(int4*)(W_bf + off) = pk.v;
}

// ---------- kernel 2: att_obj = obj @ W^T + b_obj, f32 out (round-3 verbatim) ----------
__global__ __launch_bounds__(64) void k_gemm(const float* __restrict__ obj,
                                             const unsigned short* __restrict__ W_bf,
                                             const float* __restrict__ b_obj,
                                             float* __restrict__ att_obj) {
    const int lane = threadIdx.x;
    const int xcd  = blockIdx.x & 7;
    const int j    = blockIdx.x >> 3;
    const int mt   = xcd * 13 + (j % 13);
    if (mt >= 100) return;
    const int nt   = j / 13;
    const int m0   = mt * 64;
    const int n0   = nt * 64;
    const int lr   = lane & 15;
    const int lk   = (lane >> 4) * 8;

    const float*          ap = obj  + (size_t)(m0 + lr) * DD + lk;
    const unsigned short* bp = W_bf + (size_t)(n0 + lr) * DD + lk;

    f32x4 acc[4][4];
    #pragma unroll
    for (int i = 0; i < 4; ++i)
        #pragma unroll
        for (int jj = 0; jj < 4; ++jj) acc[i][jj] = f32x4{0.f, 0.f, 0.f, 0.f};

    float4 a_lo[4], a_hi[4];
    bf16x8 bfr[4];
    #pragma unroll
    for (int i = 0; i < 4; ++i) {
        a_lo[i] = *(const float4*)(ap + (size_t)i * 16 * DD);
        a_hi[i] = *(const float4*)(ap + (size_t)i * 16 * DD + 4);
        bfr[i]  = *(const bf16x8*)(bp + (size_t)i * 16 * DD);
    }

    #pragma unroll 1
    for (int k0 = 0; k0 < DD; k0 += 32) {
        const int kn = (k0 + 32 < DD) ? (k0 + 32) : 0;
        float4 na_lo[4], na_hi[4];
        bf16x8 nb[4];
        #pragma unroll
        for (int i = 0; i < 4; ++i) {
            na_lo[i] = *(const float4*)(ap + (size_t)i * 16 * DD + kn);
            na_hi[i] = *(const float4*)(ap + (size_t)i * 16 * DD + kn + 4);
            nb[i]    = *(const bf16x8*)(bp + (size_t)i * 16 * DD + kn);
        }
        bf16x8 afr[4];
        #pragma unroll
        for (int i = 0; i < 4; ++i) {
            afr[i][0] = (__bf16)a_lo[i].x; afr[i][1] = (__bf16)a_lo[i].y;
            afr[i][2] = (__bf16)a_lo[i].z; afr[i][3] = (__bf16)a_lo[i].w;
            afr[i][4] = (__bf16)a_hi[i].x; afr[i][5] = (__bf16)a_hi[i].y;
            afr[i][6] = (__bf16)a_hi[i].z; afr[i][7] = (__bf16)a_hi[i].w;
        }
        #pragma unroll
        for (int i = 0; i < 4; ++i)
            #pragma unroll
            for (int jj = 0; jj < 4; ++jj)
                acc[i][jj] = __builtin_amdgcn_mfma_f32_16x16x32_bf16(afr[i], bfr[jj], acc[i][jj], 0, 0, 0);
        #pragma unroll
        for (int i = 0; i < 4; ++i) { a_lo[i] = na_lo[i]; a_hi[i] = na_hi[i]; bfr[i] = nb[i]; }
    }

    const int crow = (lane >> 4) * 4;
    #pragma unroll
    for (int jj = 0; jj < 4; ++jj) {
        const int n = n0 + jj * 16 + lr;
        const float bb = b_obj[n];
        #pragma unroll
        for (int i = 0; i < 4; ++i) {
            #pragma unroll
            for (int r = 0; r < 4; ++r)
                att_obj[(size_t)(m0 + i * 16 + crow + r) * HH + n] = acc[i][jj][r] + bb;
        }
    }
}

// ---------- kernel 3: fused attn (round-3 verbatim, measured ~150 us) ----------
__global__ __launch_bounds__(256) void k_attn(const float* __restrict__ att_obj,
                                              const float* __restrict__ p_attr,
                                              const int* __restrict__ masks,
                                              const float* __restrict__ w_alpha,
                                              const float* __restrict__ attr_feats,
                                              float* __restrict__ out) {
    const int wv   = threadIdx.x >> 6;
    const int lane = threadIdx.x & 63;
    const int row  = blockIdx.x * 4 + wv;

    const f32x4* att4 = (const f32x4*)(att_obj + (size_t)row * HH);
    const f32x4* wa4  = (const f32x4*)w_alpha;
    const f32x4 av0 = att4[lane],      av1 = att4[64 + lane];
    const f32x4 wv0 = wa4[lane],       wv1 = wa4[64 + lane];

    const f32x4* p4 = (const f32x4*)(p_attr + (size_t)row * AA * HH);
    float sc[AA];
    #pragma unroll 4
    for (int a = 0; a < AA; ++a) {
        f32x4 x0 = __builtin_nontemporal_load(&p4[a * 128 + lane]);
        f32x4 x1 = __builtin_nontemporal_load(&p4[a * 128 + 64 + lane]);
        float s;
        s  = wv0.x * fast_tanh(x0.x + av0.x);
        s += wv0.y * fast_tanh(x0.y + av0.y);
        s += wv0.z * fast_tanh(x0.z + av0.z);
        s += wv0.w * fast_tanh(x0.w + av0.w);
        s += wv1.x * fast_tanh(x1.x + av1.x);
        s += wv1.y * fast_tanh(x1.y + av1.y);
        s += wv1.z * fast_tanh(x1.z + av1.z);
        s += wv1.w * fast_tanh(x1.w + av1.w);
        sc[a] = s;
    }

    #pragma unroll
    for (int d = 1; d < 64; d <<= 1) {
        #pragma unroll
        for (int a = 0; a < AA; ++a) sc[a] += __shfl_xor(sc[a], d);
    }

    const int4* m4 = (const int4*)(masks + (size_t)row * AA);
    float mk[AA];
    {
        int4 m0v = m4[0], m1v = m4[1], m2v = m4[2], m3v = m4[3];
        mk[0]=(float)m0v.x; mk[1]=(float)m0v.y; mk[2]=(float)m0v.z; mk[3]=(float)m0v.w;
        mk[4]=(float)m1v.x; mk[5]=(float)m1v.y; mk[6]=(float)m1v.z; mk[7]=(float)m1v.w;
        mk[8]=(float)m2v.x; mk[9]=(float)m2v.y; mk[10]=(float)m2v.z; mk[11]=(float)m2v.w;
        mk[12]=(float)m3v.x; mk[13]=(float)m3v.y; mk[14]=(float)m3v.z; mk[15]=(float)m3v.w;
    }
    float mx = sc[0];
    #pragma unroll
    for (int a = 1; a < AA; ++a) mx = fmaxf(mx, sc[a]);
    float S = 0.f, T = 0.f;
    #pragma unroll
    for (int a = 0; a < AA; ++a) {
        float e = __expf(sc[a] - mx);
        sc[a] = e * mk[a];
        S += e;
        T += sc[a];
    }
    const float inv = 1.0f / (T + EPS * S);
    #pragma unroll
    for (int a = 0; a < AA; ++a) sc[a] *= inv;

    const f32x4* af4 = (const f32x4*)(attr_feats + (size_t)row * AA * DD);
    f32x4 acc0 = {0.f,0.f,0.f,0.f}, acc1 = acc0, acc2 = acc0, acc3 = acc0;
    #pragma unroll 4
    for (int a = 0; a < AA; ++a) {
        f32x4 v0 = __builtin_nontemporal_load(&af4[a * 256 +       lane]);
        f32x4 v1 = __builtin_nontemporal_load(&af4[a * 256 +  64 + lane]);
        f32x4 v2 = __builtin_nontemporal_load(&af4[a * 256 + 128 + lane]);
        f32x4 v3 = __builtin_nontemporal_load(&af4[a * 256 + 192 + lane]);
        const float w = sc[a];
        acc0 += w * v0;
        acc1 += w * v1;
        acc2 += w * v2;
        acc3 += w * v3;
    }
    f32x4* o4 = (f32x4*)(out + (size_t)row * DD);
    __builtin_nontemporal_store(acc0, &o4[      lane]);
    __builtin_nontemporal_store(acc1, &o4[ 64 + lane]);
    __builtin_nontemporal_store(acc2, &o4[128 + lane]);
    __builtin_nontemporal_store(acc3, &o4[192 + lane]);
}

// ---------- kernel 4: CALIBRATION — loads-only clone of k_attn ----------
// Same grid, same wave->row mapping, same load count/width/batching (4 att/wa +
// 32 NT p-like + 64 NT af-like loads, 4 stores per wave). No tanh/shfl/softmax.
// Reads the 0xAA-poisoned ws region (finite floats), writes to a ws scratch area:
// zero L3 cross-warming with the real pipeline (each kernel's 630+ MB stream evicts
// the other's lines between replays -> both HBM-cold, like standalone runs).
// C1 = dur_us(total) - 165.8 measures the pure streaming capability of this
// structure. Deterministic: same reads, same writes every call.
__global__ __launch_bounds__(256) void k_calib(const float* __restrict__ srcA,  // [6400][512] analog
                                               const float* __restrict__ srcP,  // [6400][16][512] analog
                                               const float* __restrict__ srcF,  // [6400][16][1024] analog
                                               float* __restrict__ dst) {       // [6400][1024] scratch
    const int wv   = threadIdx.x >> 6;
    const int lane = threadIdx.x & 63;
    const int row  = blockIdx.x * 4 + wv;

    const f32x4* att4 = (const f32x4*)(srcA + (size_t)row * HH);
    const f32x4* wa4  = (const f32x4*)srcA;                      // shared small region (w_alpha analog)
    f32x4 s0 = att4[lane], s1 = att4[64 + lane];
    s0 += wa4[lane]; s1 += wa4[64 + lane];

    const f32x4* p4 = (const f32x4*)(srcP + (size_t)row * AA * HH);
    #pragma unroll 4
    for (int a = 0; a < AA; ++a) {
        s0 += __builtin_nontemporal_load(&p4[a * 128 + lane]);
        s1 += __builtin_nontemporal_load(&p4[a * 128 + 64 + lane]);
    }

    const f32x4* af4 = (const f32x4*)(srcF + (size_t)row * AA * DD);
    f32x4 acc0 = {0.f,0.f,0.f,0.f}, acc1 = acc0, acc2 = acc0, acc3 = acc0;
    #pragma unroll 4
    for (int a = 0; a < AA; ++a) {
        acc0 += __builtin_nontemporal_load(&af4[a * 256 +       lane]);
        acc1 += __builtin_nontemporal_load(&af4[a * 256 +  64 + lane]);
        acc2 += __builtin_nontemporal_load(&af4[a * 256 + 128 + lane]);
        acc3 += __builtin_nontemporal_load(&af4[a * 256 + 192 + lane]);
    }
    acc0 += s0; acc1 += s1;

    f32x4* o4 = (f32x4*)(dst + (size_t)row * DD);
    __builtin_nontemporal_store(acc0, &o4[      lane]);
    __builtin_nontemporal_store(acc1, &o4[ 64 + lane]);
    __builtin_nontemporal_store(acc2, &o4[128 + lane]);
    __builtin_nontemporal_store(acc3, &o4[192 + lane]);
}

extern "C" void kernel_launch(void* const* d_in, const int* in_sizes, int n_in,
                              void* d_out, int out_size, void* d_ws, size_t ws_size,
                              hipStream_t stream) {
    const float* obj_vecs   = (const float*)d_in[0];
    const float* attr_feats = (const float*)d_in[1];
    const float* p_attr     = (const float*)d_in[2];
    const int*   masks      = (const int*)d_in[3];
    const float* W_obj      = (const float*)d_in[4];
    const float* b_obj      = (const float*)d_in[5];
    const float* w_alpha    = (const float*)d_in[6];
    float* out = (float*)d_out;

    char* ws = (char*)d_ws;
    float*          att_obj = (float*)ws;                       // 13,107,200 B
    unsigned short* W_bf    = (unsigned short*)(ws + 13107200); //  1,048,576 B

    // calibration regions (never written; hold the 0xAA poison = finite floats)
    const size_t CAL = 32ull * 1024 * 1024;
    const float* srcA = (const float*)(ws + CAL);                            // 13.1 MB
    const float* srcP = (const float*)(ws + CAL + 13107200);                 // 209.7 MB
    const float* srcF = (const float*)(ws + CAL + 13107200 + 209715200);     // 419.4 MB
    float*       cdst = (float*)(ws + CAL + 13107200 + 209715200 + 419430400); // 26.2 MB scratch

    k_prep_w<<<256, 256, 0, stream>>>(W_obj, W_bf);
    k_gemm<<<832, 64, 0, stream>>>(obj_vecs, W_bf, b_obj, att_obj);
    k_attn<<<BO / 4, 256, 0, stream>>>(att_obj, p_attr, masks, w_alpha, attr_feats, out);
    k_calib<<<BO / 4, 256, 0, stream>>>(srcA, srcP, srcF, cdst);
}

// Round 10
// 129.326 us; speedup vs baseline: 2.1520x; 2.1520x over previous
//
#include <hip/hip_runtime.h>
#include <stdint.h>

#define EPS 1e-8f

typedef __attribute__((ext_vector_type(8))) __bf16 bf16x8;
typedef __attribute__((ext_vector_type(4))) float f32x4;

static constexpr int BO = 6400;   // B*O
static constexpr int AA = 16;     // attributes
static constexpr int DD = 1024;   // D
static constexpr int HH = 512;    // H

// ---------- helpers ----------
__device__ __forceinline__ unsigned short f2bf(float x) {
    uint32_t b = __float_as_uint(x);
    b += 0x7fffu + ((b >> 16) & 1u);   // round-to-nearest-even (finite inputs)
    return (unsigned short)(b >> 16);
}

__device__ __forceinline__ float fast_tanh(float x) {
    float e = __expf(2.0f * x);
    return 1.0f - __fdividef(2.0f, e + 1.0f);
}

// ---------- kernel 1: f32 -> bf16 staging of W_obj only ----------
__global__ __launch_bounds__(256) void k_prep_w(const float* __restrict__ W,
                                                unsigned short* __restrict__ W_bf) {
    const int i = blockIdx.x * 256 + threadIdx.x;   // 65536 8-elem units
    const long off = (long)i * 8;
    float4 v0 = *(const float4*)(W + off);
    float4 v1 = *(const float4*)(W + off + 4);
    union { unsigned short u[8]; int4 v; } pk;
    pk.u[0] = f2bf(v0.x); pk.u[1] = f2bf(v0.y); pk.u[2] = f2bf(v0.z); pk.u[3] = f2bf(v0.w);
    pk.u[4] = f2bf(v1.x); pk.u[5] = f2bf(v1.y); pk.u[6] = f2bf(v1.z); pk.u[7] = f2bf(v1.w);
    *(int4*)(W_bf + off) = pk.v;
}

// ---------- kernel 2: att_obj = obj @ W^T + b_obj, f32 out (round-3 verbatim) ----------
__global__ __launch_bounds__(64) void k_gemm(const float* __restrict__ obj,
                                             const unsigned short* __restrict__ W_bf,
                                             const float* __restrict__ b_obj,
                                             float* __restrict__ att_obj) {
    const int lane = threadIdx.x;
    const int xcd  = blockIdx.x & 7;
    const int j    = blockIdx.x >> 3;
    const int mt   = xcd * 13 + (j % 13);
    if (mt >= 100) return;
    const int nt   = j / 13;
    const int m0   = mt * 64;
    const int n0   = nt * 64;
    const int lr   = lane & 15;
    const int lk   = (lane >> 4) * 8;

    const float*          ap = obj  + (size_t)(m0 + lr) * DD + lk;
    const unsigned short* bp = W_bf + (size_t)(n0 + lr) * DD + lk;

    f32x4 acc[4][4];
    #pragma unroll
    for (int i = 0; i < 4; ++i)
        #pragma unroll
        for (int jj = 0; jj < 4; ++jj) acc[i][jj] = f32x4{0.f, 0.f, 0.f, 0.f};

    float4 a_lo[4], a_hi[4];
    bf16x8 bfr[4];
    #pragma unroll
    for (int i = 0; i < 4; ++i) {
        a_lo[i] = *(const float4*)(ap + (size_t)i * 16 * DD);
        a_hi[i] = *(const float4*)(ap + (size_t)i * 16 * DD + 4);
        bfr[i]  = *(const bf16x8*)(bp + (size_t)i * 16 * DD);
    }

    #pragma unroll 1
    for (int k0 = 0; k0 < DD; k0 += 32) {
        const int kn = (k0 + 32 < DD) ? (k0 + 32) : 0;
        float4 na_lo[4], na_hi[4];
        bf16x8 nb[4];
        #pragma unroll
        for (int i = 0; i < 4; ++i) {
            na_lo[i] = *(const float4*)(ap + (size_t)i * 16 * DD + kn);
            na_hi[i] = *(const float4*)(ap + (size_t)i * 16 * DD + kn + 4);
            nb[i]    = *(const bf16x8*)(bp + (size_t)i * 16 * DD + kn);
        }
        bf16x8 afr[4];
        #pragma unroll
        for (int i = 0; i < 4; ++i) {
            afr[i][0] = (__bf16)a_lo[i].x; afr[i][1] = (__bf16)a_lo[i].y;
            afr[i][2] = (__bf16)a_lo[i].z; afr[i][3] = (__bf16)a_lo[i].w;
            afr[i][4] = (__bf16)a_hi[i].x; afr[i][5] = (__bf16)a_hi[i].y;
            afr[i][6] = (__bf16)a_hi[i].z; afr[i][7] = (__bf16)a_hi[i].w;
        }
        #pragma unroll
        for (int i = 0; i < 4; ++i)
            #pragma unroll
            for (int jj = 0; jj < 4; ++jj)
                acc[i][jj] = __builtin_amdgcn_mfma_f32_16x16x32_bf16(afr[i], bfr[jj], acc[i][jj], 0, 0, 0);
        #pragma unroll
        for (int i = 0; i < 4; ++i) { a_lo[i] = na_lo[i]; a_hi[i] = na_hi[i]; bfr[i] = nb[i]; }
    }

    const int crow = (lane >> 4) * 4;
    #pragma unroll
    for (int jj = 0; jj < 4; ++jj) {
        const int n = n0 + jj * 16 + lr;
        const float bb = b_obj[n];
        #pragma unroll
        for (int i = 0; i < 4; ++i) {
            #pragma unroll
            for (int r = 0; r < 4; ++r)
                att_obj[(size_t)(m0 + i * 16 + crow + r) * HH + n] = acc[i][jj][r] + bb;
        }
    }
}

// ---------- kernel 3: fused attn — LOW-REGISTER build ----------
// ONE WAVE PER ROW, 4 rows/block, no LDS/barriers. r9 calib proved this structure
// streams 668 MB at 5.9 TB/s when VGPR-lean; the full kernel's deficit (150 vs 112 us)
// is occupancy (register pressure), not bytes/issue/MLP (r6-r8 nulls). Changes:
//   1) mask array -> 1-VGPR bitmask; softmax in place in sc[] (saves ~32 VGPR)
//   2) __launch_bounds__(256,5): cap ~102 VGPR -> 20 waves/CU (vs ~12)
//   3) unroll 2 on load phases: 8 loads (~32 VGPR) in flight/wave; TLP covers latency
//   4) r8 address-redirect retained: masked attrs read a0's lines (L1/L2 hits),
//      halving HBM fetch now that occupancy can actually consume the bandwidth
__global__ __launch_bounds__(256, 5) void k_attn(const float* __restrict__ att_obj,   // [6400][512] f32
                                                 const float* __restrict__ p_attr,    // [6400][16][512]
                                                 const int* __restrict__ masks,       // [6400][16]
                                                 const float* __restrict__ w_alpha,   // [512]
                                                 const float* __restrict__ attr_feats,// [6400][16][1024]
                                                 float* __restrict__ out) {           // [6400][1024]
    const int wv   = threadIdx.x >> 6;
    const int lane = threadIdx.x & 63;
    const int row  = blockIdx.x * 4 + wv;

    // masks -> bitmask; a0 = first unmasked attr (redirect target)
    int mbits;
    {
        const int4* m4 = (const int4*)(masks + (size_t)row * AA);
        int4 a = m4[0], b = m4[1], c = m4[2], d = m4[3];
        mbits =  (a.x)      | (a.y << 1)  | (a.z << 2)  | (a.w << 3)
              | (b.x << 4) | (b.y << 5)  | (b.z << 6)  | (b.w << 7)
              | (c.x << 8) | (c.y << 9)  | (c.z << 10) | (c.w << 11)
              | (d.x << 12)| (d.y << 13) | (d.z << 14) | (d.w << 15);
    }
    const int a0 = mbits ? __builtin_ctz(mbits) : 0;

    const float* prow = p_attr     + (size_t)row * AA * HH;
    const float* arow = attr_feats + (size_t)row * AA * DD;

    // phase 1: per-attr partial dot; av/wv scoped to this phase
    float sc[AA];
    {
        const f32x4* att4 = (const f32x4*)(att_obj + (size_t)row * HH);
        const f32x4* wa4  = (const f32x4*)w_alpha;
        const f32x4 av0 = att4[lane], av1 = att4[64 + lane];
        const f32x4 wv0 = wa4[lane],  wv1 = wa4[64 + lane];

        #pragma unroll 2
        for (int a = 0; a < AA; ++a) {
            const f32x4* pa = (const f32x4*)(prow + (size_t)((mbits >> a & 1) ? a : a0) * HH);
            f32x4 x0 = pa[lane];
            f32x4 x1 = pa[64 + lane];
            float s;
            s  = wv0.x * fast_tanh(x0.x + av0.x);
            s += wv0.y * fast_tanh(x0.y + av0.y);
            s += wv0.z * fast_tanh(x0.z + av0.z);
            s += wv0.w * fast_tanh(x0.w + av0.w);
            s += wv1.x * fast_tanh(x1.x + av1.x);
            s += wv1.y * fast_tanh(x1.y + av1.y);
            s += wv1.z * fast_tanh(x1.z + av1.z);
            s += wv1.w * fast_tanh(x1.w + av1.w);
            sc[a] = s;
        }
    }

    // cross-lane butterfly: every lane ends with all 16 full scores
    #pragma unroll
    for (int d = 1; d < 64; d <<= 1) {
        #pragma unroll
        for (int a = 0; a < AA; ++a) sc[a] += __shfl_xor(sc[a], d);
    }

    // phase 2: softmax over unmasked + renorm, IN PLACE (b_alpha cancels;
    // masked e == 0 -> denom = T*(1+EPS), r8-validated; guard all-masked)
    float mx = -3.0e38f;
    #pragma unroll
    for (int a = 0; a < AA; ++a)
        if (mbits >> a & 1) mx = fmaxf(mx, sc[a]);
    float T = 0.f;
    #pragma unroll
    for (int a = 0; a < AA; ++a) {
        float e = (mbits >> a & 1) ? __expf(sc[a] - mx) : 0.f;
        sc[a] = e;
        T += e;
    }
    const float inv = (T > 0.f) ? 1.0f / (T * (1.0f + EPS)) : 0.f;
    #pragma unroll
    for (int a = 0; a < AA; ++a) sc[a] *= inv;

    // phase 3: streaming weighted pooling, redirected addresses, unroll 2
    f32x4 acc0 = {0.f,0.f,0.f,0.f}, acc1 = acc0, acc2 = acc0, acc3 = acc0;
    #pragma unroll 2
    for (int a = 0; a < AA; ++a) {
        const f32x4* a4 = (const f32x4*)(arow + (size_t)((mbits >> a & 1) ? a : a0) * DD);
        f32x4 v0 = a4[       lane];
        f32x4 v1 = a4[ 64 + lane];
        f32x4 v2 = a4[128 + lane];
        f32x4 v3 = a4[192 + lane];
        const float w = sc[a];
        acc0 += w * v0;
        acc1 += w * v1;
        acc2 += w * v2;
        acc3 += w * v3;
    }
    f32x4* o4 = (f32x4*)(out + (size_t)row * DD);
    o4[      lane] = acc0;
    o4[ 64 + lane] = acc1;
    o4[128 + lane] = acc2;
    o4[192 + lane] = acc3;
}

extern "C" void kernel_launch(void* const* d_in, const int* in_sizes, int n_in,
                              void* d_out, int out_size, void* d_ws, size_t ws_size,
                              hipStream_t stream) {
    const float* obj_vecs   = (const float*)d_in[0];
    const float* attr_feats = (const float*)d_in[1];
    const float* p_attr     = (const float*)d_in[2];
    const int*   masks      = (const int*)d_in[3];
    const float* W_obj      = (const float*)d_in[4];
    const float* b_obj      = (const float*)d_in[5];
    const float* w_alpha    = (const float*)d_in[6];
    // d_in[7] = b_alpha: uniform additive shift before softmax -> cancels exactly
    float* out = (float*)d_out;

    char* ws = (char*)d_ws;
    float*          att_obj = (float*)ws;                       // 13,107,200 B
    unsigned short* W_bf    = (unsigned short*)(ws + 13107200); //  1,048,576 B
    // total ws use: 14,155,776 B

    k_prep_w<<<256, 256, 0, stream>>>(W_obj, W_bf);
    k_gemm<<<832, 64, 0, stream>>>(obj_vecs, W_bf, b_obj, att_obj);
    k_attn<<<BO / 4, 256, 0, stream>>>(att_obj, p_attr, masks, w_alpha, attr_feats, out);
}